// Round 8
// baseline (106.980 us; speedup 1.0000x reference)
//
#include <hip/hip_runtime.h>
#include <hip/hip_bf16.h>
#include <math.h>

// B=8, T=128, D=512. M = 1024 rows, N = 6*512 = 3072 concatenated outputs.
// Stage 0: split fp32 -> (hi,lo) bf16, packed per 32-K super-chunk (R7).
// Stage 1: software-pipelined bf16 MFMA GEMM, dbuf LDS (R7).
// Stage 2: fused branches via degree-24 Taylor moments. R8: 128 thr/block
//          (2 waves), 4 j's + 4 i's per lane -> 2 waves/SIMD TLP; moment
//          reduce split across waves. R6's 1-wave/SIMD had zero TLP.

#define M_ROWS 1024
#define DIMD   512
#define NCOLS  3072
#define KPHYS  1024

typedef __attribute__((ext_vector_type(8))) short short8;
typedef __attribute__((ext_vector_type(4))) float f32x4;
typedef __attribute__((ext_vector_type(4))) unsigned short u16x4;

struct PtrArgs {
    const float* W[6];
    const float* b[6];
};

#define XN (M_ROWS * DIMD)
#define WN (NCOLS * DIMD)

__device__ __forceinline__ unsigned short bf16_rne(float v) {
    unsigned u = __float_as_uint(v);
    u = (u + 0x7FFFu + ((u >> 16) & 1u)) >> 16;
    return (unsigned short)u;
}

__device__ __constant__ float INVFACT[25] = {
    1.0f, 1.0f, 0.5f,
    1.6666666666666666e-01f, 4.1666666666666664e-02f, 8.3333333333333332e-03f,
    1.3888888888888889e-03f, 1.9841269841269841e-04f, 2.4801587301587302e-05f,
    2.7557319223985893e-06f, 2.7557319223985888e-07f, 2.5052108385441720e-08f,
    2.0876756987868100e-09f, 1.6059043836821613e-10f, 1.1470745597729725e-11f,
    7.6471637318198164e-13f, 4.7794773323873853e-14f, 2.8114572543455206e-15f,
    1.5619206968586225e-16f, 8.2206352466243295e-18f, 4.1103176233121648e-19f,
    1.9572941063391263e-20f, 8.8967913924505741e-22f, 3.8681701706306835e-23f,
    1.6117375710961184e-24f
};

// ---------------------------------------------------------------------------
// Stage 0: convert/split, float4-vectorized (unchanged from R7).
// ---------------------------------------------------------------------------
__global__ __launch_bounds__(256) void convert_split(const float* __restrict__ x,
                                                     PtrArgs pa,
                                                     unsigned short* __restrict__ Aph,
                                                     unsigned short* __restrict__ Bph,
                                                     float* __restrict__ biasAll) {
    const int idx = blockIdx.x * 256 + threadIdx.x;   // vec4 index
    if (idx < NCOLS) {
        biasAll[idx] = pa.b[idx >> 9][idx & 511];
    }
    const int e4 = idx * 4;
    if (e4 < XN) {
        int m = e4 >> 9, k = e4 & 511;
        int s = k >> 5, p = k & 31;
        float4 v = *(const float4*)(x + e4);
        u16x4 hi, lo;
        hi.x = bf16_rne(v.x); lo.x = bf16_rne(v.x - __uint_as_float(((unsigned)hi.x) << 16));
        hi.y = bf16_rne(v.y); lo.y = bf16_rne(v.y - __uint_as_float(((unsigned)hi.y) << 16));
        hi.z = bf16_rne(v.z); lo.z = bf16_rne(v.z - __uint_as_float(((unsigned)hi.z) << 16));
        hi.w = bf16_rne(v.w); lo.w = bf16_rne(v.w - __uint_as_float(((unsigned)hi.w) << 16));
        *(u16x4*)&Aph[(size_t)m * KPHYS + s * 64 + p]      = hi;
        *(u16x4*)&Aph[(size_t)m * KPHYS + s * 64 + 32 + p] = lo;
    } else if (e4 < XN + WN) {
        int j = e4 - XN;
        int n = j >> 9, k = j & 511;
        int g = n >> 9, o = n & 511;
        int s = k >> 5, p = k & 31;
        float4 v = *(const float4*)(pa.W[g] + (size_t)o * DIMD + k);
        u16x4 hi, lo;
        hi.x = bf16_rne(v.x); lo.x = bf16_rne(v.x - __uint_as_float(((unsigned)hi.x) << 16));
        hi.y = bf16_rne(v.y); lo.y = bf16_rne(v.y - __uint_as_float(((unsigned)hi.y) << 16));
        hi.z = bf16_rne(v.z); lo.z = bf16_rne(v.z - __uint_as_float(((unsigned)hi.z) << 16));
        hi.w = bf16_rne(v.w); lo.w = bf16_rne(v.w - __uint_as_float(((unsigned)hi.w) << 16));
        *(u16x4*)&Bph[(size_t)n * KPHYS + s * 64 + p]      = hi;
        *(u16x4*)&Bph[(size_t)n * KPHYS + s * 64 + 32 + p] = lo;
    }
}

// ---------------------------------------------------------------------------
// Stage 1: software-pipelined MFMA GEMM (unchanged from R7).
// ---------------------------------------------------------------------------
__global__ __launch_bounds__(256) void gemm_mfma(const unsigned short* __restrict__ A,
                                                 const unsigned short* __restrict__ B,
                                                 const float* __restrict__ biasAll,
                                                 float* __restrict__ Y) {
    __shared__ __align__(16) short As[2][64 * 64];
    __shared__ __align__(16) short Bs[2][128 * 64];

    const int tid  = threadIdx.x;
    const int m0   = blockIdx.y * 64;
    const int n0   = blockIdx.x * 128;
    const int lane = tid & 63;
    const int w    = tid >> 6;
    const int wm   = w & 1;
    const int wn   = w >> 1;
    const int l15  = lane & 15;
    const int quad = lane >> 4;

    f32x4 acc[2][4];
    #pragma unroll
    for (int i = 0; i < 2; ++i)
        #pragma unroll
        for (int j = 0; j < 4; ++j)
            acc[i][j] = (f32x4){0.f, 0.f, 0.f, 0.f};

    auto stage = [&](int it, int buf) {
        const int kbase = it * 64;
        #pragma unroll
        for (int t = 0; t < 2; ++t) {
            int idx = t * 256 + tid;
            int r = idx >> 3, c = idx & 7;
            int cc = c ^ (r & 7);
            const unsigned short* ga = A + (size_t)(m0 + r) * KPHYS + kbase + cc * 8;
            __builtin_amdgcn_global_load_lds(
                (const __attribute__((address_space(1))) unsigned int*)ga,
                (__attribute__((address_space(3))) unsigned int*)&As[buf][idx * 8], 16, 0, 0);
        }
        #pragma unroll
        for (int t = 0; t < 4; ++t) {
            int idx = t * 256 + tid;
            int r = idx >> 3, c = idx & 7;
            int cc = c ^ (r & 7);
            const unsigned short* gb = B + (size_t)(n0 + r) * KPHYS + kbase + cc * 8;
            __builtin_amdgcn_global_load_lds(
                (const __attribute__((address_space(1))) unsigned int*)gb,
                (__attribute__((address_space(3))) unsigned int*)&Bs[buf][idx * 8], 16, 0, 0);
        }
    };

    stage(0, 0);

    for (int it = 0; it < 16; ++it) {
        __syncthreads();
        if (it + 1 < 16) stage(it + 1, (it + 1) & 1);

        const short* as = As[it & 1];
        const short* bs = Bs[it & 1];
        short8 ah[2], al[2], bh[4], bl[4];
        #pragma unroll
        for (int mt = 0; mt < 2; ++mt) {
            int rA = wm * 32 + mt * 16 + l15;
            int ch = quad ^ (rA & 7);
            int cl = (4 + quad) ^ (rA & 7);
            ah[mt] = *(const short8*)&as[(rA * 8 + ch) * 8];
            al[mt] = *(const short8*)&as[(rA * 8 + cl) * 8];
        }
        #pragma unroll
        for (int nt = 0; nt < 4; ++nt) {
            int rB = wn * 64 + nt * 16 + l15;
            int ch = quad ^ (rB & 7);
            int cl = (4 + quad) ^ (rB & 7);
            bh[nt] = *(const short8*)&bs[(rB * 8 + ch) * 8];
            bl[nt] = *(const short8*)&bs[(rB * 8 + cl) * 8];
        }
        #pragma unroll
        for (int mt = 0; mt < 2; ++mt)
            #pragma unroll
            for (int nt = 0; nt < 4; ++nt) {
                acc[mt][nt] = __builtin_amdgcn_mfma_f32_16x16x32_bf16(
                    ah[mt], bh[nt], acc[mt][nt], 0, 0, 0);
                acc[mt][nt] = __builtin_amdgcn_mfma_f32_16x16x32_bf16(
                    ah[mt], bl[nt], acc[mt][nt], 0, 0, 0);
                acc[mt][nt] = __builtin_amdgcn_mfma_f32_16x16x32_bf16(
                    al[mt], bh[nt], acc[mt][nt], 0, 0, 0);
            }
    }

    #pragma unroll
    for (int nt = 0; nt < 4; ++nt) {
        int col = n0 + wn * 64 + nt * 16 + l15;
        float bv = biasAll[col];
        #pragma unroll
        for (int mt = 0; mt < 2; ++mt) {
            int row0 = m0 + wm * 32 + mt * 16 + quad * 4;
            #pragma unroll
            for (int r = 0; r < 4; ++r)
                Y[(size_t)(row0 + r) * NCOLS + col] = acc[mt][nt][r] + bv;
        }
    }
}

// ---------------------------------------------------------------------------
// Stage 2: fused branches. R8: 128 threads (2 waves) per (b,t) row; lane
// owns 4 contiguous i's/j's (i0 = 4*t). Moments in registers -> LDS
// transpose (part[128][51], odd stride: writes 2-way/free, column reads
// conflict-free). Reduce split: wave0 sums rows 0..63, wave1 rows 64..127.
// ---------------------------------------------------------------------------
#define PSTR 51

__global__ __launch_bounds__(128) void fused_attn(const float* __restrict__ Y,
                                                  float* __restrict__ out) {
    const int row  = blockIdx.x;
    const int t    = threadIdx.x;       // 0..127
    const int lane = t & 63;
    const int wv   = t >> 6;
    const float* __restrict__ Yr = Y + (size_t)row * NCOLS;
    const int i0 = t * 4;

    __shared__ float part[128 * PSTR];  // 26.1 KB
    __shared__ float red0[50];
    __shared__ float red1[50];
    __shared__ float cbuf[50];
    __shared__ float sred[2];

    const float LOG2E = 1.4426950408889634f;

    float4 qf4 = *(const float4*)(Yr + i0);
    float4 kf4 = *(const float4*)(Yr + 512 + i0);
    float4 vf4 = *(const float4*)(Yr + 1024 + i0);
    float4 qt4 = *(const float4*)(Yr + 1536 + i0);
    float4 kt4 = *(const float4*)(Yr + 2048 + i0);
    float4 vt4 = *(const float4*)(Yr + 2560 + i0);

    // ---- feature branch: 4 exps + block sum ----
    float e0 = __builtin_amdgcn_exp2f(qf4.x * kf4.x * LOG2E);
    float e1 = __builtin_amdgcn_exp2f(qf4.y * kf4.y * LOG2E);
    float e2 = __builtin_amdgcn_exp2f(qf4.z * kf4.z * LOG2E);
    float e3 = __builtin_amdgcn_exp2f(qf4.w * kf4.w * LOG2E);
    float psum = (e0 + e1) + (e2 + e3);
    #pragma unroll
    for (int off = 32; off; off >>= 1) psum += __shfl_xor(psum, off);
    if (lane == 0) sred[wv] = psum;

    // ---- temporal moments over this lane's 4 j's ----
    float k0 = kt4.x, k1 = kt4.y, k2 = kt4.z, k3 = kt4.w;
    float v0 = vt4.x, v1 = vt4.y, v2 = vt4.z, v3 = vt4.w;
    float p0 = 1.f, p1 = 1.f, p2 = 1.f, p3 = 1.f;
    float* myrow = &part[t * PSTR];
    #pragma unroll
    for (int p = 0; p < 25; ++p) {
        float n = (p0 + p1) + (p2 + p3);
        float m = fmaf(p3, v3, fmaf(p2, v2, fmaf(p1, v1, p0 * v0)));
        myrow[p]      = m;
        myrow[25 + p] = n;
        p0 *= k0; p1 *= k1; p2 *= k2; p3 *= k3;
    }
    __syncthreads();

    // ---- split transpose-reduce: wave0 rows 0..63, wave1 rows 64..127 ----
    if (lane < 50) {
        const int rbase = wv * 64;
        float s = 0.f;
        #pragma unroll
        for (int r = 0; r < 64; ++r) s += part[(rbase + r) * PSTR + lane];
        if (wv == 0) red0[lane] = s; else red1[lane] = s;
    }
    __syncthreads();
    if (t < 50) {
        cbuf[t] = (red0[t] + red1[t]) * INVFACT[t < 25 ? t : t - 25];
    }
    __syncthreads();

    const float invS = 1.0f / (sred[0] + sred[1]);

    // ---- Horner for 4 i's ----
    float qa = qt4.x, qb = qt4.y, qc = qt4.z, qd = qt4.w;
    float Fa, Fb, Fc, Fd, Ga, Gb, Gc, Gd;
    {
        float cf = cbuf[24], cg = cbuf[49];
        Fa = Fb = Fc = Fd = cf;
        Ga = Gb = Gc = Gd = cg;
    }
    #pragma unroll
    for (int p = 23; p >= 0; --p) {
        float cf = cbuf[p], cg = cbuf[25 + p];
        Fa = fmaf(Fa, qa, cf); Ga = fmaf(Ga, qa, cg);
        Fb = fmaf(Fb, qb, cf); Gb = fmaf(Gb, qb, cg);
        Fc = fmaf(Fc, qc, cf); Gc = fmaf(Gc, qc, cg);
        Fd = fmaf(Fd, qd, cf); Gd = fmaf(Gd, qd, cg);
    }

    float4 o;
    o.x = e0 * invS * vf4.x + Fa / Ga;
    o.y = e1 * invS * vf4.y + Fb / Gb;
    o.z = e2 * invS * vf4.z + Fc / Gc;
    o.w = e3 * invS * vf4.w + Fd / Gd;
    *(float4*)(out + (size_t)row * DIMD + i0) = o;
}

extern "C" void kernel_launch(void* const* d_in, const int* in_sizes, int n_in,
                              void* d_out, int out_size, void* d_ws, size_t ws_size,
                              hipStream_t stream) {
    const float* x = (const float*)d_in[0];
    PtrArgs pa;
    for (int g = 0; g < 6; ++g) {
        pa.W[g] = (const float*)d_in[1 + 2 * g];
        pa.b[g] = (const float*)d_in[2 + 2 * g];
    }

    // Workspace layout:
    //   Y:    [1024][3072] fp32  = 12,582,912 B
    //   Aph:  [1024][1024] bf16  =  2,097,152 B
    //   Bph:  [3072][1024] bf16  =  6,291,456 B
    //   bias: [3072] fp32        =     12,288 B
    char* ws = (char*)d_ws;
    float*          Y    = (float*)ws;
    unsigned short* Aph  = (unsigned short*)(ws + 12582912);
    unsigned short* Bph  = (unsigned short*)(ws + 12582912 + 2097152);
    float*          bias = (float*)(ws + 12582912 + 2097152 + 6291456);

    convert_split<<<(XN + WN) / 4 / 256, 256, 0, stream>>>(x, pa, Aph, Bph, bias);

    dim3 g1(NCOLS / 128, M_ROWS / 64);   // 24 x 16 = 384 blocks
    gemm_mfma<<<g1, 256, 0, stream>>>(Aph, Bph, bias, Y);

    fused_attn<<<M_ROWS, 128, 0, stream>>>(Y, (float*)d_out);
}